// Round 2
// baseline (359.125 us; speedup 1.0000x reference)
//
#include <hip/hip_runtime.h>

typedef unsigned short u16;
typedef unsigned int u32;
typedef __bf16 bf16x8 __attribute__((ext_vector_type(8)));
typedef float f32x4 __attribute__((ext_vector_type(4)));

// ---------- helpers ----------

__device__ __forceinline__ u16 f2bf(float f) {  // round-to-nearest-even fp32->bf16
  u32 u = __builtin_bit_cast(u32, f);
  u32 r = (u + 0x7fffu + ((u >> 16) & 1u)) >> 16;
  return (u16)r;
}
__device__ __forceinline__ u32 pk2(float a, float b) {
  return (u32)f2bf(a) | ((u32)f2bf(b) << 16);
}
__device__ __forceinline__ f32x4 mfma16(bf16x8 a, bf16x8 b, f32x4 c) {
  return __builtin_amdgcn_mfma_f32_16x16x32_bf16(a, b, c, 0, 0, 0);
}
// async global->LDS, 16B/lane; LDS dest = wave-uniform base + lane*16
__device__ __forceinline__ void glds16(const void* g, void* l) {
  typedef __attribute__((address_space(1))) void as1_void;
  typedef __attribute__((address_space(3))) void as3_void;
  __builtin_amdgcn_global_load_lds((as1_void*)g, (as3_void*)l, 16, 0, 0);
}

// ---------- kernel 1: x fp32 -> bf16 ----------

__launch_bounds__(256)
__global__ void convert_x_k(const float* __restrict__ in, u16* __restrict__ out) {
  long i = ((long)blockIdx.x * 256 + threadIdx.x) * 8;
  float4 f0 = *(const float4*)(in + i);
  float4 f1 = *(const float4*)(in + i + 4);
  uint4 o;
  o.x = pk2(f0.x, f0.y);
  o.y = pk2(f0.z, f0.w);
  o.z = pk2(f1.x, f1.y);
  o.w = pk2(f1.z, f1.w);
  *(uint4*)(out + i) = o;
}

// ---------- kernel 2: W [K][N] fp32 -> Wt [N][K] bf16 ----------

__launch_bounds__(256)
__global__ void transpose_w_k(const float* __restrict__ in, u16* __restrict__ out,
                              int K, int N) {
  __shared__ float t[32][33];
  int n0 = blockIdx.x * 32, k0 = blockIdx.y * 32;
  int tx = threadIdx.x & 31, ty = threadIdx.x >> 5;  // 8 rows per pass
#pragma unroll
  for (int s = 0; s < 32; s += 8)
    t[ty + s][tx] = in[(long)(k0 + ty + s) * N + n0 + tx];
  __syncthreads();
#pragma unroll
  for (int s = 0; s < 32; s += 8)
    out[(long)(n0 + ty + s) * K + k0 + tx] = f2bf(t[tx][ty + s]);
}

// ---------- kernel 3: attn_bias [h][256][256] -> MFMA D-layout float4 table ----------
// biasT[((h*16+rt)*16 + jt)*64 + lane] (float4): elem r = bias[h][rt*16+quad*4+r][jt*16+l15]

__launch_bounds__(256)
__global__ void bias_transform_k(const float* __restrict__ bias, float* __restrict__ biasT) {
  int hb = blockIdx.x;  // h*16 + rt
  int h = hb >> 4, rt = hb & 15;
  int lane = threadIdx.x & 63;
  int quad = lane >> 4, l15 = lane & 15;
  int jtg = threadIdx.x >> 6;  // 0..3
#pragma unroll
  for (int i = 0; i < 4; ++i) {
    int jt = jtg * 4 + i;
    const float* src = bias + ((long)h * 256 + rt * 16 + quad * 4) * 256 + jt * 16 + l15;
    float4 v;
    v.x = src[0]; v.y = src[256]; v.z = src[512]; v.w = src[768];
    *(float4*)&biasT[(((long)hb * 16 + jt) * 64 + lane) * 4] = v;
  }
}

// ---------- kernels 4/6: C = A(bf16 [M][512]) * Bt(bf16 [N][512])^T + bias ----------
// 128x128 tile, BK=64, 4 waves, 4x4 MFMA 16x16x32 tiles per wave.
// LDS chunk-major [c][row][32] with XOR swizzle: 16B group position = g ^ ((row>>1)&3)
// -> conflict-free b128 frag reads (each 8-lane phase covers all 8 bank slots).
// Output: natural row-major, bf16 (OUTFP32=0) or fp32 (OUTFP32=1).

template <int OUTFP32>
__launch_bounds__(256)
__global__ void gemm_bt(const u16* __restrict__ A, const u16* __restrict__ Bt,
                        const float* __restrict__ bias, int N,
                        u16* __restrict__ obf, float* __restrict__ ofp) {
  constexpr int K = 512;
  __shared__ u16 Asm[8192];  // block b = c*512 + row*4 + pos; pos holds group g = pos^((row>>1)&3)
  __shared__ u16 Bsm[8192];

  const int tid = threadIdx.x;
  const int wave = tid >> 6, lane = tid & 63;
  const int quad = lane >> 4, l15 = lane & 15;
  const int wm = wave >> 1, wn = wave & 1;
  const int gsw = quad ^ ((l15 >> 1) & 3);  // swizzled group position for frag reads
  const long arow0 = (long)blockIdx.y * 128;
  const long brow0 = (long)blockIdx.x * 128;

  f32x4 acc[4][4] = {};

  for (int k0 = 0; k0 < K; k0 += 64) {
#pragma unroll
    for (int rd = 0; rd < 4; ++rd) {
      int flat = rd * 256 + tid;  // 16B-block index 0..1023
      int c = flat >> 9, row = (flat >> 2) & 127, gp = flat & 3;
      int g = gp ^ ((row >> 1) & 3);  // global group stored at position gp
      const long koff = k0 + c * 32 + g * 8;
      glds16(A + (arow0 + row) * K + koff, &Asm[(rd * 256 + wave * 64) * 8]);
      glds16(Bt + (brow0 + row) * K + koff, &Bsm[(rd * 256 + wave * 64) * 8]);
    }
    __syncthreads();
#pragma unroll
    for (int c = 0; c < 2; ++c) {
      bf16x8 af[4], bfr[4];
#pragma unroll
      for (int i = 0; i < 4; ++i)
        af[i] = *(const bf16x8*)&Asm[c * 4096 + (wm * 64 + i * 16 + l15) * 32 + gsw * 8];
#pragma unroll
      for (int j = 0; j < 4; ++j)
        bfr[j] = *(const bf16x8*)&Bsm[c * 4096 + (wn * 64 + j * 16 + l15) * 32 + gsw * 8];
#pragma unroll
      for (int i = 0; i < 4; ++i)
#pragma unroll
        for (int j = 0; j < 4; ++j)
          acc[i][j] = mfma16(af[i], bfr[j], acc[i][j]);
    }
    __syncthreads();
  }

  // epilogue: D-layout row = quad*4 + r, col = l15; natural row-major store
#pragma unroll
  for (int j = 0; j < 4; ++j) {
    const int C = (int)brow0 + wn * 64 + j * 16 + l15;
    const float bc = bias[C];
#pragma unroll
    for (int i = 0; i < 4; ++i) {
      const long R0 = arow0 + wm * 64 + i * 16 + quad * 4;
#pragma unroll
      for (int r = 0; r < 4; ++r) {
        const float val = acc[i][j][r] + bc;
        if constexpr (OUTFP32) ofp[(R0 + r) * N + C] = val;
        else                   obf[(R0 + r) * N + C] = f2bf(val);
      }
    }
  }
}

// ---------- kernel 5: block-local attention, one block per (b,h,window) ----------
// qkv natural [32768][1536] bf16 (cols: 0-511 q, 512-1023 k, 1024-1535 v).
// vT built in-LDS (rows -> t2 -> chunk-major swizzled). Per wave: 4 sub-chunks of
// 16 q-rows; wave-local softmax; P through per-wave LDS (swizzled); PV MFMA.
// Output: natural [32768][512] bf16.

__launch_bounds__(256)
__global__ void attn_win(const u16* __restrict__ qkv, const float* __restrict__ biasT,
                         u16* __restrict__ og) {
  __shared__ u16 smem[32768];  // [0,16384): vT  |  [16384,32768): t2 (phase1) / P (4x4096)

  const int tid = threadIdx.x;
  const int wave = tid >> 6, lane = tid & 63;
  const int quad = lane >> 4, l15 = lane & 15;
  const int gsw = quad ^ ((l15 >> 1) & 3);

  const int wi = blockIdx.x;
  const int nwi = wi & 31, hi = (wi >> 5) & 7, bi = wi >> 8;
  const long grow = (long)bi * 8192 + nwi * 256;
  const u16* qp = qkv + grow * 1536 + hi * 64;
  const u16* kp = qp + 512;
  const u16* vp = qp + 1024;

  u16* vT = smem;
  u16* t2 = smem + 16384;

  // phase 1a: v rows -> t2 [256][64]  (coalesced 16B loads)
#pragma unroll
  for (int it = 0; it < 8; ++it) {
    int flat = it * 256 + tid;
    int w = flat >> 3, dg = flat & 7;
    int4 val = *(const int4*)&vp[(long)w * 1536 + dg * 8];
    *(int4*)&t2[w * 64 + dg * 8] = val;
  }
  __syncthreads();
  // phase 1b: transpose -> vT chunk-major [kk][d][32], swizzled group position
#pragma unroll
  for (int it = 0; it < 8; ++it) {
    int flat = it * 256 + tid;
    int d = flat & 63, wg = flat >> 6;  // wg 0..31 (w-group of 8)
    u16 tmp[8];
#pragma unroll
    for (int j = 0; j < 8; ++j) tmp[j] = t2[(wg * 8 + j) * 64 + d];
    int gp = (wg & 3) ^ ((d >> 1) & 3);
    int4 val;
    __builtin_memcpy(&val, tmp, 16);
    *(int4*)&vT[(wg >> 2) * 2048 + d * 32 + gp * 8] = val;
  }
  __syncthreads();

  u16* Pw = smem + 16384 + wave * 4096;
  const float scale = 0.125f;  // 64^-0.5

  for (int sc = 0; sc < 4; ++sc) {
    const int q0 = wave * 64 + sc * 16;
    const int rt = wave * 4 + sc;  // q0 >> 4

    bf16x8 aq0 = *(const bf16x8*)&qp[(long)(q0 + l15) * 1536 + quad * 8];
    bf16x8 aq1 = *(const bf16x8*)&qp[(long)(q0 + l15) * 1536 + 32 + quad * 8];

    f32x4 s[16];
#pragma unroll
    for (int jt = 0; jt < 16; ++jt) {
      const u16* kr = &kp[(long)(jt * 16 + l15) * 1536];
      bf16x8 b0 = *(const bf16x8*)&kr[quad * 8];
      bf16x8 b1 = *(const bf16x8*)&kr[32 + quad * 8];
      f32x4 z = {0.f, 0.f, 0.f, 0.f};
      z = mfma16(aq0, b0, z);
      z = mfma16(aq1, b1, z);
      s[jt] = z;
    }

    // scale + bias from D-layout float4 table (coalesced)
#pragma unroll
    for (int jt = 0; jt < 16; ++jt) {
      f32x4 bb = *(const f32x4*)&biasT[(((long)(hi * 16 + rt) * 16 + jt) * 64 + lane) * 4];
#pragma unroll
      for (int r = 0; r < 4; ++r) s[jt][r] = s[jt][r] * scale + bb[r];
    }

    // wave-local softmax: row lives in this quad's 16 lanes x 16 regs
    float inv[4];
#pragma unroll
    for (int r = 0; r < 4; ++r) {
      float m = s[0][r];
#pragma unroll
      for (int jt = 1; jt < 16; ++jt) m = fmaxf(m, s[jt][r]);
#pragma unroll
      for (int off = 1; off < 16; off <<= 1) m = fmaxf(m, __shfl_xor(m, off, 16));
      float sum = 0.f;
#pragma unroll
      for (int jt = 0; jt < 16; ++jt) {
        float p = __expf(s[jt][r] - m);
        s[jt][r] = p;
        sum += p;
      }
#pragma unroll
      for (int off = 1; off < 16; off <<= 1) sum += __shfl_xor(sum, off, 16);
      inv[r] = 1.0f / sum;
    }

    // P -> per-wave LDS, A-layout chunk-major with swizzle
#pragma unroll
    for (int jt = 0; jt < 16; ++jt) {
      const int kk = jt >> 1;
      const int gbase = (jt & 1) * 2 + (l15 >> 3);
      const int elem = l15 & 7;
#pragma unroll
      for (int r = 0; r < 4; ++r) {
        const int m = quad * 4 + r;
        const int gp = gbase ^ ((m >> 1) & 3);
        Pw[kk * 512 + m * 32 + gp * 8 + elem] = f2bf(s[jt][r]);
      }
    }

    // O = P v : K=256 over 8 k-steps (same-wave LDS, no barrier needed)
    f32x4 o[4] = {};
#pragma unroll
    for (int kk = 0; kk < 8; ++kk) {
      bf16x8 ap = *(const bf16x8*)&Pw[kk * 512 + l15 * 32 + gsw * 8];
#pragma unroll
      for (int dt = 0; dt < 4; ++dt) {
        bf16x8 bv = *(const bf16x8*)&vT[kk * 2048 + (dt * 16 + l15) * 32 + gsw * 8];
        o[dt] = mfma16(ap, bv, o[dt]);
      }
    }

    // epilogue: divide by rowsum, store natural [b*8192+n][512]
    const long rowbase = (grow + q0 + quad * 4) * 512 + hi * 64;
#pragma unroll
    for (int dt = 0; dt < 4; ++dt)
#pragma unroll
      for (int r = 0; r < 4; ++r)
        og[rowbase + (long)r * 512 + dt * 16 + l15] = f2bf(o[dt][r] * inv[r]);
  }
}

// ---------- launcher ----------

extern "C" void kernel_launch(void* const* d_in, const int* in_sizes, int n_in,
                              void* d_out, int out_size, void* d_ws, size_t ws_size,
                              hipStream_t stream) {
  const float* x     = (const float*)d_in[0];
  const float* Wqkv  = (const float*)d_in[1];
  const float* bqkv  = (const float*)d_in[2];
  const float* Wproj = (const float*)d_in[3];
  const float* bproj = (const float*)d_in[4];
  const float* abias = (const float*)d_in[5];
  float* out = (float*)d_out;

  // workspace layout (bytes):
  //   qkv bf16 [32768][1536]: 100,663,296
  //   WqkvT bf16: 1,572,864 | WprojT bf16: 524,288 | biasT fp32: 2,097,152
  //   x_bf16 [32768][512] (aliased as attn_out after qkv GEMM consumes it): 33,554,432
  char* ws = (char*)d_ws;
  u16*   qkvp   = (u16*)(ws);
  u16*   wqkvT  = (u16*)(ws + 100663296L);
  u16*   wprojT = (u16*)(ws + 102236160L);
  float* biasTp = (float*)(ws + 102760448L);
  u16*   xbf    = (u16*)(ws + 104857600L);
  u16*   attnout = xbf;  // safe: x_bf16 dead after qkv GEMM (stream-ordered)

  convert_x_k<<<8192, 256, 0, stream>>>(x, xbf);
  transpose_w_k<<<dim3(48, 16), 256, 0, stream>>>(Wqkv, wqkvT, 512, 1536);
  transpose_w_k<<<dim3(16, 16), 256, 0, stream>>>(Wproj, wprojT, 512, 512);
  bias_transform_k<<<128, 256, 0, stream>>>(abias, biasTp);
  gemm_bt<0><<<dim3(12, 256), 256, 0, stream>>>(xbf, wqkvT, bqkv, 1536,
                                                qkvp, nullptr);
  attn_win<<<1024, 256, 0, stream>>>(qkvp, biasTp, attnout);
  gemm_bt<1><<<dim3(4, 256), 256, 0, stream>>>(attnout, wprojT, bproj, 512,
                                               nullptr, out);
}

// Round 3
// 345.280 us; speedup vs baseline: 1.0401x; 1.0401x over previous
//
#include <hip/hip_runtime.h>

typedef unsigned short u16;
typedef unsigned int u32;
typedef __bf16 bf16x8 __attribute__((ext_vector_type(8)));
typedef float f32x4 __attribute__((ext_vector_type(4)));

// ---------- helpers ----------

__device__ __forceinline__ u16 f2bf(float f) {  // round-to-nearest-even fp32->bf16
  u32 u = __builtin_bit_cast(u32, f);
  u32 r = (u + 0x7fffu + ((u >> 16) & 1u)) >> 16;
  return (u16)r;
}
__device__ __forceinline__ u32 pk2(float a, float b) {
  return (u32)f2bf(a) | ((u32)f2bf(b) << 16);
}
__device__ __forceinline__ f32x4 mfma16(bf16x8 a, bf16x8 b, f32x4 c) {
  return __builtin_amdgcn_mfma_f32_16x16x32_bf16(a, b, c, 0, 0, 0);
}
// async global->LDS, 16B/lane; LDS dest = wave-uniform base + lane*16
__device__ __forceinline__ void glds16(const void* g, void* l) {
  typedef __attribute__((address_space(1))) void as1_void;
  typedef __attribute__((address_space(3))) void as3_void;
  __builtin_amdgcn_global_load_lds((as1_void*)g, (as3_void*)l, 16, 0, 0);
}

// ---------- kernel 1: x fp32 -> bf16 ----------

__launch_bounds__(256)
__global__ void convert_x_k(const float* __restrict__ in, u16* __restrict__ out) {
  long i = ((long)blockIdx.x * 256 + threadIdx.x) * 8;
  float4 f0 = *(const float4*)(in + i);
  float4 f1 = *(const float4*)(in + i + 4);
  uint4 o;
  o.x = pk2(f0.x, f0.y);
  o.y = pk2(f0.z, f0.w);
  o.z = pk2(f1.x, f1.y);
  o.w = pk2(f1.z, f1.w);
  *(uint4*)(out + i) = o;
}

// ---------- kernel 2: W [K][N] fp32 -> Wt [N][K] bf16 ----------

__launch_bounds__(256)
__global__ void transpose_w_k(const float* __restrict__ in, u16* __restrict__ out,
                              int K, int N) {
  __shared__ float t[32][33];
  int n0 = blockIdx.x * 32, k0 = blockIdx.y * 32;
  int tx = threadIdx.x & 31, ty = threadIdx.x >> 5;  // 8 rows per pass
#pragma unroll
  for (int s = 0; s < 32; s += 8)
    t[ty + s][tx] = in[(long)(k0 + ty + s) * N + n0 + tx];
  __syncthreads();
#pragma unroll
  for (int s = 0; s < 32; s += 8)
    out[(long)(n0 + ty + s) * K + k0 + tx] = f2bf(t[tx][ty + s]);
}

// ---------- kernel 3: bias -> S^T D-layout table, pre-scaled by log2(e) ----------
// biasT[((h*16+rt)*16 + jt)*64 + lane] (float4):
//   elem r = bias[h][q = rt*16+l15][t = jt*16+quad*4+r] * log2(e)

__launch_bounds__(256)
__global__ void bias_transform_k(const float* __restrict__ bias, float* __restrict__ biasT) {
  int hb = blockIdx.x;  // h*16 + rt
  int h = hb >> 4, rt = hb & 15;
  int lane = threadIdx.x & 63;
  int quad = lane >> 4, l15 = lane & 15;
  int jtg = threadIdx.x >> 6;  // 0..3
  const float L = 1.44269504f;
#pragma unroll
  for (int i = 0; i < 4; ++i) {
    int jt = jtg * 4 + i;
    float4 v = *(const float4*)&bias[((long)h * 256 + rt * 16 + l15) * 256 + jt * 16 + quad * 4];
    v.x *= L; v.y *= L; v.z *= L; v.w *= L;
    *(float4*)&biasT[(((long)hb * 16 + jt) * 64 + lane) * 4] = v;
  }
}

// ---------- kernels 4/6: C = A(bf16 [M][512]) * Bt(bf16 [N][512])^T + bias ----------
// 128x128 tile, BK=64, 4 waves, 4x4 MFMA 16x16x32 tiles per wave.
// LDS chunk-major [c][row][32] with XOR swizzle (pos = g ^ ((row>>1)&3)).
// EPI=0: q/k cols -> natural [32768][1024] bf16; v cols -> v^T [(b*8+h)*64+d][8192] bf16
//        (packed 8B stores along n).
// EPI=1: fp32 row-major [32768][512] output (d_out).

template <int EPI>
__launch_bounds__(256)
__global__ void gemm_bt(const u16* __restrict__ A, const u16* __restrict__ Bt,
                        const float* __restrict__ bias,
                        u16* __restrict__ oqk, u16* __restrict__ ovt,
                        float* __restrict__ ofp) {
  constexpr int K = 512;
  __shared__ u16 Asm[8192];
  __shared__ u16 Bsm[8192];

  const int tid = threadIdx.x;
  const int wave = tid >> 6, lane = tid & 63;
  const int quad = lane >> 4, l15 = lane & 15;
  const int wm = wave >> 1, wn = wave & 1;
  const int gsw = quad ^ ((l15 >> 1) & 3);
  const long arow0 = (long)blockIdx.y * 128;
  const long brow0 = (long)blockIdx.x * 128;

  f32x4 acc[4][4] = {};

  for (int k0 = 0; k0 < K; k0 += 64) {
#pragma unroll
    for (int rd = 0; rd < 4; ++rd) {
      int flat = rd * 256 + tid;  // 16B-block index 0..1023
      int c = flat >> 9, row = (flat >> 2) & 127, gp = flat & 3;
      int g = gp ^ ((row >> 1) & 3);
      const long koff = k0 + c * 32 + g * 8;
      glds16(A + (arow0 + row) * K + koff, &Asm[(rd * 256 + wave * 64) * 8]);
      glds16(Bt + (brow0 + row) * K + koff, &Bsm[(rd * 256 + wave * 64) * 8]);
    }
    __syncthreads();
#pragma unroll
    for (int c = 0; c < 2; ++c) {
      bf16x8 af[4], bfr[4];
#pragma unroll
      for (int i = 0; i < 4; ++i)
        af[i] = *(const bf16x8*)&Asm[c * 4096 + (wm * 64 + i * 16 + l15) * 32 + gsw * 8];
#pragma unroll
      for (int j = 0; j < 4; ++j)
        bfr[j] = *(const bf16x8*)&Bsm[c * 4096 + (wn * 64 + j * 16 + l15) * 32 + gsw * 8];
#pragma unroll
      for (int i = 0; i < 4; ++i)
#pragma unroll
        for (int j = 0; j < 4; ++j)
          acc[i][j] = mfma16(af[i], bfr[j], acc[i][j]);
    }
    __syncthreads();
  }

  // epilogue: D-layout row = quad*4 + r, col = l15
#pragma unroll
  for (int j = 0; j < 4; ++j) {
    const int C = (int)brow0 + wn * 64 + j * 16 + l15;
    const float bc = bias[C];
#pragma unroll
    for (int i = 0; i < 4; ++i) {
      const long R0 = arow0 + wm * 64 + i * 16 + quad * 4;
      float v4[4];
#pragma unroll
      for (int r = 0; r < 4; ++r) v4[r] = acc[i][j][r] + bc;
      if constexpr (EPI == 0) {
        if (C < 1024) {  // q/k: natural rows (wave-uniform branch)
#pragma unroll
          for (int r = 0; r < 4; ++r) oqk[(R0 + r) * 1024 + C] = f2bf(v4[r]);
        } else {         // v: transposed, packed 8B along n
          const int hc = (C >> 6) & 7, dc = C & 63;
          const int b = (int)(R0 >> 13), n0 = (int)(R0 & 8191);
          uint2 w;
          w.x = pk2(v4[0], v4[1]);
          w.y = pk2(v4[2], v4[3]);
          *(uint2*)&ovt[((long)(b * 8 + hc) * 64 + dc) * 8192 + n0] = w;
        }
      } else {
#pragma unroll
        for (int r = 0; r < 4; ++r) ofp[(R0 + r) * 512 + C] = v4[r];
      }
    }
  }
}

// ---------- kernel 5: block-local attention, one block per (b,h,window) ----------
// S^T = K Q^T formulation: D-layout col = q = l15 -> in-lane softmax rows,
// scalar 1/sum per lane, packed P writes, packed O stores.
// k staged in swizzled LDS (A-frags = ds_read_b128); v^T pre-transposed by GEMM,
// staged coalesced; P per-wave 4-chunk buffer (no barriers after staging).

__launch_bounds__(256)
__global__ void attn_win(const u16* __restrict__ qk, const u16* __restrict__ vtb,
                         const float* __restrict__ biasT, u16* __restrict__ og) {
  __shared__ __align__(16) u16 kS[16384];   // [c][256 t][32], pos = g^((t>>1)&3)   32 KB
  __shared__ __align__(16) u16 vS[16384];   // [kk 8][64 d][32], pos = g^((d>>1)&3) 32 KB
  __shared__ __align__(16) u16 pS[4][2048]; // per-wave [kkl 4][16 q][32], swizzled 16 KB

  const int tid = threadIdx.x;
  const int wave = tid >> 6, lane = tid & 63;
  const int quad = lane >> 4, l15 = lane & 15;
  const int gsw = quad ^ ((l15 >> 1) & 3);

  const int wi = blockIdx.x;
  const int nwi = wi & 31, hi = (wi >> 5) & 7, bi = wi >> 8;
  const long grow = (long)bi * 8192 + nwi * 256;
  const u16* qp = qk + grow * 1024 + hi * 64;
  const u16* kp = qp + 512;
  const u16* vp = vtb + (long)(bi * 8 + hi) * 64 * 8192 + nwi * 256;  // [d][256]

  // stage k rows -> chunk-major swizzled LDS
#pragma unroll
  for (int it = 0; it < 8; ++it) {
    int flat = it * 256 + tid;
    int t = flat >> 3, dg = flat & 7;
    int c = dg >> 2, gp = (dg & 3) ^ ((t >> 1) & 3);
    int4 val = *(const int4*)&kp[(long)t * 1024 + dg * 8];
    *(int4*)&kS[c * 8192 + t * 32 + gp * 8] = val;
  }
  // stage v^T rows -> chunk-major swizzled LDS (coalesced: 512B per d-row)
#pragma unroll
  for (int it = 0; it < 8; ++it) {
    int flat = it * 256 + tid;
    int d = flat >> 5, tg = flat & 31;
    int kk = tg >> 2, gp = (tg & 3) ^ ((d >> 1) & 3);
    int4 val = *(const int4*)&vp[(long)d * 8192 + tg * 8];
    *(int4*)&vS[kk * 2048 + d * 32 + gp * 8] = val;
  }
  __syncthreads();

  u16* Pw = pS[wave];
  const float cscale = 0.18033688f;  // 64^-0.5 * log2(e)

  for (int sc = 0; sc < 4; ++sc) {
    const int q0 = wave * 64 + sc * 16;
    const int rt = wave * 4 + sc;

    // q B-frags from global (2 loads; 64B/row fully-used lines)
    bf16x8 bq0 = *(const bf16x8*)&qp[(long)(q0 + l15) * 1024 + quad * 8];
    bf16x8 bq1 = *(const bf16x8*)&qp[(long)(q0 + l15) * 1024 + 32 + quad * 8];

    // S^T = K Q^T : A = k frags from LDS
    f32x4 s[16];
#pragma unroll
    for (int jt = 0; jt < 16; ++jt) {
      bf16x8 a0 = *(const bf16x8*)&kS[(jt * 16 + l15) * 32 + gsw * 8];
      bf16x8 a1 = *(const bf16x8*)&kS[8192 + (jt * 16 + l15) * 32 + gsw * 8];
      f32x4 z = {0.f, 0.f, 0.f, 0.f};
      z = mfma16(a0, bq0, z);
      z = mfma16(a1, bq1, z);
      s[jt] = z;
    }

    // scale+bias in exp2 domain (D-layout float4 table, coalesced, L2-hot)
#pragma unroll
    for (int jt = 0; jt < 16; ++jt) {
      f32x4 bb = *(const f32x4*)&biasT[(((long)(hi * 16 + rt) * 16 + jt) * 64 + lane) * 4];
#pragma unroll
      for (int r = 0; r < 4; ++r) s[jt][r] = s[jt][r] * cscale + bb[r];
    }

    // softmax over t: in-lane reduce + 2 cross-quad shuffles
    f32x4 m4 = s[0];
#pragma unroll
    for (int jt = 1; jt < 16; ++jt)
#pragma unroll
      for (int r = 0; r < 4; ++r) m4[r] = fmaxf(m4[r], s[jt][r]);
    float m = fmaxf(fmaxf(m4[0], m4[1]), fmaxf(m4[2], m4[3]));
    m = fmaxf(m, __shfl_xor(m, 16));
    m = fmaxf(m, __shfl_xor(m, 32));

    f32x4 sum4 = {0.f, 0.f, 0.f, 0.f};
#pragma unroll
    for (int jt = 0; jt < 16; ++jt)
#pragma unroll
      for (int r = 0; r < 4; ++r) {
        float p = __builtin_exp2f(s[jt][r] - m);
        s[jt][r] = p;
        sum4[r] += p;
      }
    float sum = (sum4[0] + sum4[1]) + (sum4[2] + sum4[3]);
    sum += __shfl_xor(sum, 16);
    sum += __shfl_xor(sum, 32);
    const float inv = 1.0f / sum;

    // PV in 2 halves of 4 k-chunks: packed P writes -> b128 reads -> MFMA
    f32x4 o[4] = {};
#pragma unroll
    for (int h2 = 0; h2 < 2; ++h2) {
#pragma unroll
      for (int kk2 = 0; kk2 < 4; ++kk2) {
#pragma unroll
        for (int e = 0; e < 2; ++e) {  // jt parity within chunk
          int jt = h2 * 8 + kk2 * 2 + e;
          int gp = (e * 2 + (quad >> 1)) ^ ((l15 >> 1) & 3);
          uint2 w;
          w.x = pk2(s[jt][0], s[jt][1]);
          w.y = pk2(s[jt][2], s[jt][3]);
          *(uint2*)&Pw[kk2 * 512 + l15 * 32 + gp * 8 + (quad & 1) * 4] = w;
        }
      }
#pragma unroll
      for (int kk2 = 0; kk2 < 4; ++kk2) {
        int kk = h2 * 4 + kk2;
        bf16x8 bp = *(const bf16x8*)&Pw[kk2 * 512 + l15 * 32 + gsw * 8];
#pragma unroll
        for (int dt = 0; dt < 4; ++dt) {
          bf16x8 av = *(const bf16x8*)&vS[kk * 2048 + (dt * 16 + l15) * 32 + gsw * 8];
          o[dt] = mfma16(av, bp, o[dt]);  // O^T[d][q]
        }
      }
    }

    // store: lane holds 4 consecutive d per dt at row n = grow+q0+l15 -> 8B packs
    const long rowoff = (grow + q0 + l15) * 512 + hi * 64 + quad * 4;
#pragma unroll
    for (int dt = 0; dt < 4; ++dt) {
      uint2 w;
      w.x = pk2(o[dt][0] * inv, o[dt][1] * inv);
      w.y = pk2(o[dt][2] * inv, o[dt][3] * inv);
      *(uint2*)&og[rowoff + dt * 16] = w;
    }
  }
}

// ---------- launcher ----------

extern "C" void kernel_launch(void* const* d_in, const int* in_sizes, int n_in,
                              void* d_out, int out_size, void* d_ws, size_t ws_size,
                              hipStream_t stream) {
  const float* x     = (const float*)d_in[0];
  const float* Wqkv  = (const float*)d_in[1];
  const float* bqkv  = (const float*)d_in[2];
  const float* Wproj = (const float*)d_in[3];
  const float* bproj = (const float*)d_in[4];
  const float* abias = (const float*)d_in[5];
  float* out = (float*)d_out;

  // workspace layout (bytes):
  //   qk natural bf16 [32768][1024]: 67,108,864
  //   v^T bf16 [2048][8192]:         33,554,432   (ends 100,663,296)
  //   WqkvT bf16: 1,572,864 | WprojT bf16: 524,288 | biasT fp32: 2,097,152
  //   x_bf16 [32768][512] (aliased as attn_out after qkv GEMM): 33,554,432
  char* ws = (char*)d_ws;
  u16*   qkp    = (u16*)(ws);
  u16*   vtb    = (u16*)(ws + 67108864L);
  u16*   wqkvT  = (u16*)(ws + 100663296L);
  u16*   wprojT = (u16*)(ws + 102236160L);
  float* biasTp = (float*)(ws + 102760448L);
  u16*   xbf    = (u16*)(ws + 104857600L);
  u16*   attnout = xbf;  // safe: x_bf16 dead after qkv GEMM (stream-ordered)

  convert_x_k<<<8192, 256, 0, stream>>>(x, xbf);
  transpose_w_k<<<dim3(48, 16), 256, 0, stream>>>(Wqkv, wqkvT, 512, 1536);
  transpose_w_k<<<dim3(16, 16), 256, 0, stream>>>(Wproj, wprojT, 512, 512);
  bias_transform_k<<<128, 256, 0, stream>>>(abias, biasTp);
  gemm_bt<0><<<dim3(12, 256), 256, 0, stream>>>(xbf, wqkvT, bqkv,
                                                qkp, vtb, nullptr);
  attn_win<<<1024, 256, 0, stream>>>(qkp, vtb, biasTp, attnout);
  gemm_bt<1><<<dim3(4, 256), 256, 0, stream>>>(attnout, wprojT, bproj,
                                               nullptr, nullptr, out);
}

// Round 4
// 309.402 us; speedup vs baseline: 1.1607x; 1.1160x over previous
//
#include <hip/hip_runtime.h>

typedef unsigned short u16;
typedef unsigned int u32;
typedef __bf16 bf16x8 __attribute__((ext_vector_type(8)));
typedef float f32x4 __attribute__((ext_vector_type(4)));

// ---------- helpers ----------

__device__ __forceinline__ u16 f2bf(float f) {  // round-to-nearest-even fp32->bf16
  u32 u = __builtin_bit_cast(u32, f);
  u32 r = (u + 0x7fffu + ((u >> 16) & 1u)) >> 16;
  return (u16)r;
}
__device__ __forceinline__ u32 pk2(float a, float b) {
  return (u32)f2bf(a) | ((u32)f2bf(b) << 16);
}
__device__ __forceinline__ f32x4 mfma16(bf16x8 a, bf16x8 b, f32x4 c) {
  return __builtin_amdgcn_mfma_f32_16x16x32_bf16(a, b, c, 0, 0, 0);
}
// async global->LDS, 16B/lane; LDS dest = wave-uniform base + lane*16
__device__ __forceinline__ void glds16(const void* g, void* l) {
  typedef __attribute__((address_space(1))) void as1_void;
  typedef __attribute__((address_space(3))) void as3_void;
  __builtin_amdgcn_global_load_lds((as1_void*)g, (as3_void*)l, 16, 0, 0);
}

// ---------- kernel 1: x fp32 -> bf16 ----------

__launch_bounds__(256)
__global__ void convert_x_k(const float* __restrict__ in, u16* __restrict__ out) {
  long i = ((long)blockIdx.x * 256 + threadIdx.x) * 8;
  float4 f0 = *(const float4*)(in + i);
  float4 f1 = *(const float4*)(in + i + 4);
  uint4 o;
  o.x = pk2(f0.x, f0.y);
  o.y = pk2(f0.z, f0.w);
  o.z = pk2(f1.x, f1.y);
  o.w = pk2(f1.z, f1.w);
  *(uint4*)(out + i) = o;
}

// ---------- kernel 2: W [K][N] fp32 -> Wt [N][K] bf16 ----------

__launch_bounds__(256)
__global__ void transpose_w_k(const float* __restrict__ in, u16* __restrict__ out,
                              int K, int N) {
  __shared__ float t[32][33];
  int n0 = blockIdx.x * 32, k0 = blockIdx.y * 32;
  int tx = threadIdx.x & 31, ty = threadIdx.x >> 5;  // 8 rows per pass
#pragma unroll
  for (int s = 0; s < 32; s += 8)
    t[ty + s][tx] = in[(long)(k0 + ty + s) * N + n0 + tx];
  __syncthreads();
#pragma unroll
  for (int s = 0; s < 32; s += 8)
    out[(long)(n0 + ty + s) * K + k0 + tx] = f2bf(t[tx][ty + s]);
}

// ---------- kernel 3: bias -> S^T D-layout table, pre-scaled by log2(e) ----------
// biasT[((h*16+rt)*16 + jt)*64 + lane] (float4):
//   elem r = bias[h][q = rt*16+l15][t = jt*16+quad*4+r] * log2(e)

__launch_bounds__(256)
__global__ void bias_transform_k(const float* __restrict__ bias, float* __restrict__ biasT) {
  int hb = blockIdx.x;  // h*16 + rt
  int h = hb >> 4, rt = hb & 15;
  int lane = threadIdx.x & 63;
  int quad = lane >> 4, l15 = lane & 15;
  int jtg = threadIdx.x >> 6;  // 0..3
  const float L = 1.44269504f;
#pragma unroll
  for (int i = 0; i < 4; ++i) {
    int jt = jtg * 4 + i;
    float4 v = *(const float4*)&bias[((long)h * 256 + rt * 16 + l15) * 256 + jt * 16 + quad * 4];
    v.x *= L; v.y *= L; v.z *= L; v.w *= L;
    *(float4*)&biasT[(((long)hb * 16 + jt) * 64 + lane) * 4] = v;
  }
}

// ---------- kernels 4/6: C = A(bf16 [M][512]) * Bt(bf16 [N][512])^T + bias ----------
// 128x128 tile, BK=64, 4 waves, 4x4 MFMA 16x16x32 tiles per wave.
// LDS chunk-major [c][row][32] with XOR swizzle (pos = g ^ ((row>>1)&3)).
// EPI=0: q/k cols -> natural [32768][1024] bf16; v cols -> v^T [(b*8+h)*64+d][8192] bf16.
// EPI=1: fp32 row-major [32768][512] output (d_out).

template <int EPI>
__launch_bounds__(256)
__global__ void gemm_bt(const u16* __restrict__ A, const u16* __restrict__ Bt,
                        const float* __restrict__ bias,
                        u16* __restrict__ oqk, u16* __restrict__ ovt,
                        float* __restrict__ ofp) {
  constexpr int K = 512;
  __shared__ u16 Asm[8192];
  __shared__ u16 Bsm[8192];

  const int tid = threadIdx.x;
  const int wave = tid >> 6, lane = tid & 63;
  const int quad = lane >> 4, l15 = lane & 15;
  const int wm = wave >> 1, wn = wave & 1;
  const int gsw = quad ^ ((l15 >> 1) & 3);
  const long arow0 = (long)blockIdx.y * 128;
  const long brow0 = (long)blockIdx.x * 128;

  f32x4 acc[4][4] = {};

  for (int k0 = 0; k0 < K; k0 += 64) {
#pragma unroll
    for (int rd = 0; rd < 4; ++rd) {
      int flat = rd * 256 + tid;  // 16B-block index 0..1023
      int c = flat >> 9, row = (flat >> 2) & 127, gp = flat & 3;
      int g = gp ^ ((row >> 1) & 3);
      const long koff = k0 + c * 32 + g * 8;
      glds16(A + (arow0 + row) * K + koff, &Asm[(rd * 256 + wave * 64) * 8]);
      glds16(Bt + (brow0 + row) * K + koff, &Bsm[(rd * 256 + wave * 64) * 8]);
    }
    __syncthreads();
#pragma unroll
    for (int c = 0; c < 2; ++c) {
      bf16x8 af[4], bfr[4];
#pragma unroll
      for (int i = 0; i < 4; ++i)
        af[i] = *(const bf16x8*)&Asm[c * 4096 + (wm * 64 + i * 16 + l15) * 32 + gsw * 8];
#pragma unroll
      for (int j = 0; j < 4; ++j)
        bfr[j] = *(const bf16x8*)&Bsm[c * 4096 + (wn * 64 + j * 16 + l15) * 32 + gsw * 8];
#pragma unroll
      for (int i = 0; i < 4; ++i)
#pragma unroll
        for (int j = 0; j < 4; ++j)
          acc[i][j] = mfma16(af[i], bfr[j], acc[i][j]);
    }
    __syncthreads();
  }

  // epilogue: D-layout row = quad*4 + r, col = l15
#pragma unroll
  for (int j = 0; j < 4; ++j) {
    const int C = (int)brow0 + wn * 64 + j * 16 + l15;
    const float bc = bias[C];
#pragma unroll
    for (int i = 0; i < 4; ++i) {
      const long R0 = arow0 + wm * 64 + i * 16 + quad * 4;
      float v4[4];
#pragma unroll
      for (int r = 0; r < 4; ++r) v4[r] = acc[i][j][r] + bc;
      if constexpr (EPI == 0) {
        if (C < 1024) {  // q/k: natural rows (wave-uniform branch)
#pragma unroll
          for (int r = 0; r < 4; ++r) oqk[(R0 + r) * 1024 + C] = f2bf(v4[r]);
        } else {         // v: transposed, packed 8B along n
          const int hc = (C >> 6) & 7, dc = C & 63;
          const int b = (int)(R0 >> 13), n0 = (int)(R0 & 8191);
          uint2 w;
          w.x = pk2(v4[0], v4[1]);
          w.y = pk2(v4[2], v4[3]);
          *(uint2*)&ovt[((long)(b * 8 + hc) * 64 + dc) * 8192 + n0] = w;
        }
      } else {
#pragma unroll
        for (int r = 0; r < 4; ++r) ofp[(R0 + r) * 512 + C] = v4[r];
      }
    }
  }
}

// ---------- kernel 5: block-local attention, one 512-thread block per (b,h,window) ----------
// S^T = K Q^T formulation. Streaming no-max softmax (scores bounded ~|2|: exp2 safe):
// per jt: kS b128 -> 2 MFMA -> fused fma+exp2 -> pack -> 8B P-write; PV interleaved
// every 2 k-chunks via 2KB/wave P buffer (same-wave DS is in-order; no barriers).
// 8 waves x 32 q-rows. LDS 80KB -> 2 blocks/CU; VGPR capped 128 -> 16 waves/CU.

__launch_bounds__(512, 4)
__global__ void attn_win(const u16* __restrict__ qk, const u16* __restrict__ vtb,
                         const float* __restrict__ biasT, u16* __restrict__ og) {
  __shared__ __align__(16) u16 kS[16384];    // [c][256 t][32], pos = g^((t>>1)&3)   32 KB
  __shared__ __align__(16) u16 vS[16384];    // [kk 8][64 d][32], pos = g^((d>>1)&3) 32 KB
  __shared__ __align__(16) u16 pS[8][1024];  // per-wave 2 slots x [16 q][32 t]      16 KB

  const int tid = threadIdx.x;
  const int wave = tid >> 6, lane = tid & 63;
  const int quad = lane >> 4, l15 = lane & 15;
  const int gsw = quad ^ ((l15 >> 1) & 3);

  const int wi = blockIdx.x;
  const int nwi = wi & 31, hi = (wi >> 5) & 7, bi = wi >> 8;
  const long grow = (long)bi * 8192 + nwi * 256;
  const u16* qp = qk + grow * 1024 + hi * 64;
  const u16* kp = qp + 512;
  const u16* vp = vtb + (long)(bi * 8 + hi) * 64 * 8192 + nwi * 256;  // [d][256]

  // stage k rows -> chunk-major swizzled LDS (512 threads: 4 iters)
#pragma unroll
  for (int it = 0; it < 4; ++it) {
    int flat = it * 512 + tid;
    int t = flat >> 3, dg = flat & 7;
    int c = dg >> 2, gp = (dg & 3) ^ ((t >> 1) & 3);
    int4 val = *(const int4*)&kp[(long)t * 1024 + dg * 8];
    *(int4*)&kS[c * 8192 + t * 32 + gp * 8] = val;
  }
  // stage v^T rows -> chunk-major swizzled LDS (coalesced 512B/d-row)
#pragma unroll
  for (int it = 0; it < 4; ++it) {
    int flat = it * 512 + tid;
    int d = flat >> 5, tg = flat & 31;
    int kk = tg >> 2, gp = (tg & 3) ^ ((d >> 1) & 3);
    int4 val = *(const int4*)&vp[(long)d * 8192 + tg * 8];
    *(int4*)&vS[kk * 2048 + d * 32 + gp * 8] = val;
  }
  __syncthreads();

  u16* Pw = pS[wave];
  const float cscale = 0.18033688f;  // 64^-0.5 * log2(e)

#pragma unroll
  for (int sc = 0; sc < 2; ++sc) {
    const int q0 = wave * 32 + sc * 16;
    const int rt = wave * 2 + sc;
    const float* bT = &biasT[(long)(hi * 16 + rt) * 16 * 64 * 4];

    // q B-frags from global (L2-hot; 64B/row fully-used lines)
    bf16x8 bq0 = *(const bf16x8*)&qp[(long)(q0 + l15) * 1024 + quad * 8];
    bf16x8 bq1 = *(const bf16x8*)&qp[(long)(q0 + l15) * 1024 + 32 + quad * 8];

    f32x4 sum4 = {0.f, 0.f, 0.f, 0.f};
    f32x4 o[4] = {};

#pragma unroll
    for (int m = 0; m < 4; ++m) {
      // S-stream: 4 jt -> exp2 -> P slots (kk = m*2, m*2+1)
#pragma unroll
      for (int j2 = 0; j2 < 4; ++j2) {
        const int jt = m * 4 + j2;
        bf16x8 a0 = *(const bf16x8*)&kS[(jt * 16 + l15) * 32 + gsw * 8];
        bf16x8 a1 = *(const bf16x8*)&kS[8192 + (jt * 16 + l15) * 32 + gsw * 8];
        f32x4 z = {0.f, 0.f, 0.f, 0.f};
        z = mfma16(a0, bq0, z);
        z = mfma16(a1, bq1, z);
        f32x4 bb = *(const f32x4*)&bT[(long)jt * 256 + lane * 4];
        f32x4 p;
#pragma unroll
        for (int r = 0; r < 4; ++r) {
          p[r] = __builtin_exp2f(z[r] * cscale + bb[r]);
          sum4[r] += p[r];
        }
        const int gp = ((jt & 1) * 2 + (quad >> 1)) ^ ((l15 >> 1) & 3);
        const int slot = (jt >> 1) & 1;
        uint2 w;
        w.x = pk2(p[0], p[1]);
        w.y = pk2(p[2], p[3]);
        *(uint2*)&Pw[slot * 512 + l15 * 32 + gp * 8 + (quad & 1) * 4] = w;
      }
      // PV for the 2 completed chunks (same-wave DS in-order; no barrier)
#pragma unroll
      for (int kk2 = 0; kk2 < 2; ++kk2) {
        const int kk = m * 2 + kk2;
        bf16x8 bp = *(const bf16x8*)&Pw[kk2 * 512 + l15 * 32 + gsw * 8];
#pragma unroll
        for (int dt = 0; dt < 4; ++dt) {
          bf16x8 av = *(const bf16x8*)&vS[kk * 2048 + (dt * 16 + l15) * 32 + gsw * 8];
          o[dt] = mfma16(av, bp, o[dt]);  // O^T[d][q]
        }
      }
    }

    // rowsum -> inv (q = l15 lives in-lane; 2 cross-quad shuffles)
    float sum = (sum4[0] + sum4[1]) + (sum4[2] + sum4[3]);
    sum += __shfl_xor(sum, 16);
    sum += __shfl_xor(sum, 32);
    const float inv = 1.0f / sum;

    // store: lane holds 4 consecutive d per dt at row n = grow+q0+l15 -> 8B packs
    const long rowoff = (grow + q0 + l15) * 512 + hi * 64 + quad * 4;
#pragma unroll
    for (int dt = 0; dt < 4; ++dt) {
      uint2 w;
      w.x = pk2(o[dt][0] * inv, o[dt][1] * inv);
      w.y = pk2(o[dt][2] * inv, o[dt][3] * inv);
      *(uint2*)&og[rowoff + dt * 16] = w;
    }
  }
}

// ---------- launcher ----------

extern "C" void kernel_launch(void* const* d_in, const int* in_sizes, int n_in,
                              void* d_out, int out_size, void* d_ws, size_t ws_size,
                              hipStream_t stream) {
  const float* x     = (const float*)d_in[0];
  const float* Wqkv  = (const float*)d_in[1];
  const float* bqkv  = (const float*)d_in[2];
  const float* Wproj = (const float*)d_in[3];
  const float* bproj = (const float*)d_in[4];
  const float* abias = (const float*)d_in[5];
  float* out = (float*)d_out;

  // workspace layout (bytes):
  //   qk natural bf16 [32768][1024]: 67,108,864
  //   v^T bf16 [2048][8192]:         33,554,432   (ends 100,663,296)
  //   WqkvT bf16: 1,572,864 | WprojT bf16: 524,288 | biasT fp32: 2,097,152
  //   x_bf16 [32768][512] (aliased as attn_out after qkv GEMM): 33,554,432
  char* ws = (char*)d_ws;
  u16*   qkp    = (u16*)(ws);
  u16*   vtb    = (u16*)(ws + 67108864L);
  u16*   wqkvT  = (u16*)(ws + 100663296L);
  u16*   wprojT = (u16*)(ws + 102236160L);
  float* biasTp = (float*)(ws + 102760448L);
  u16*   xbf    = (u16*)(ws + 104857600L);
  u16*   attnout = xbf;  // safe: x_bf16 dead after qkv GEMM (stream-ordered)

  convert_x_k<<<8192, 256, 0, stream>>>(x, xbf);
  transpose_w_k<<<dim3(48, 16), 256, 0, stream>>>(Wqkv, wqkvT, 512, 1536);
  transpose_w_k<<<dim3(16, 16), 256, 0, stream>>>(Wproj, wprojT, 512, 512);
  bias_transform_k<<<128, 256, 0, stream>>>(abias, biasTp);
  gemm_bt<0><<<dim3(12, 256), 256, 0, stream>>>(xbf, wqkvT, bqkv,
                                                qkp, vtb, nullptr);
  attn_win<<<1024, 512, 0, stream>>>(qkp, vtb, biasTp, attnout);
  gemm_bt<1><<<dim3(4, 256), 256, 0, stream>>>(attnout, wprojT, bproj,
                                               nullptr, nullptr, out);
}

// Round 5
// 280.933 us; speedup vs baseline: 1.2783x; 1.1013x over previous
//
#include <hip/hip_runtime.h>

typedef unsigned short u16;
typedef unsigned int u32;
typedef __bf16 bf16x8 __attribute__((ext_vector_type(8)));
typedef float f32x4 __attribute__((ext_vector_type(4)));

// ---------- helpers ----------

__device__ __forceinline__ u16 f2bf(float f) {  // round-to-nearest-even fp32->bf16
  u32 u = __builtin_bit_cast(u32, f);
  u32 r = (u + 0x7fffu + ((u >> 16) & 1u)) >> 16;
  return (u16)r;
}
__device__ __forceinline__ u32 pk2(float a, float b) {
  return (u32)f2bf(a) | ((u32)f2bf(b) << 16);
}
__device__ __forceinline__ f32x4 mfma16(bf16x8 a, bf16x8 b, f32x4 c) {
  return __builtin_amdgcn_mfma_f32_16x16x32_bf16(a, b, c, 0, 0, 0);
}
// async global->LDS, 16B/lane; LDS dest = wave-uniform base + lane*16
__device__ __forceinline__ void glds16(const void* g, void* l) {
  typedef __attribute__((address_space(1))) void as1_void;
  typedef __attribute__((address_space(3))) void as3_void;
  __builtin_amdgcn_global_load_lds((as1_void*)g, (as3_void*)l, 16, 0, 0);
}

// ---------- kernel 1: fused prep ----------
// blocks [0,8192): x fp32->bf16 | [8192,8960): Wqkv^T | [8960,9216): Wproj^T
// [9216,9344): bias -> S^T D-layout table pre-scaled by log2(e)

__device__ __forceinline__ void transpose_body(const float* __restrict__ in,
                                               u16* __restrict__ out,
                                               int N, int n0, int k0) {
  __shared__ float t[32][33];
  int tx = threadIdx.x & 31, ty = threadIdx.x >> 5;  // 8 rows per pass
#pragma unroll
  for (int s = 0; s < 32; s += 8)
    t[ty + s][tx] = in[(long)(k0 + ty + s) * N + n0 + tx];
  __syncthreads();
#pragma unroll
  for (int s = 0; s < 32; s += 8)
    out[(long)(n0 + ty + s) * 512 + k0 + tx] = f2bf(t[tx][ty + s]);
}

__launch_bounds__(256)
__global__ void prep_k(const float* __restrict__ x, u16* __restrict__ xbf,
                       const float* __restrict__ Wqkv, u16* __restrict__ wqkvT,
                       const float* __restrict__ Wproj, u16* __restrict__ wprojT,
                       const float* __restrict__ bias, float* __restrict__ biasT) {
  const int id = blockIdx.x;
  if (id < 8192) {
    long i = ((long)id * 256 + threadIdx.x) * 8;
    float4 f0 = *(const float4*)(x + i);
    float4 f1 = *(const float4*)(x + i + 4);
    uint4 o;
    o.x = pk2(f0.x, f0.y);
    o.y = pk2(f0.z, f0.w);
    o.z = pk2(f1.x, f1.y);
    o.w = pk2(f1.z, f1.w);
    *(uint4*)(xbf + i) = o;
  } else if (id < 8960) {
    int bx = id - 8192;  // 768 = 48 x 16
    transpose_body(Wqkv, wqkvT, 1536, (bx % 48) * 32, (bx / 48) * 32);
  } else if (id < 9216) {
    int bx = id - 8960;  // 256 = 16 x 16
    transpose_body(Wproj, wprojT, 512, (bx & 15) * 32, (bx >> 4) * 32);
  } else {
    int hb = id - 9216;  // h*16 + rt
    int h = hb >> 4, rt = hb & 15;
    int lane = threadIdx.x & 63;
    int quad = lane >> 4, l15 = lane & 15;
    int jtg = threadIdx.x >> 6;  // 0..3
    const float L = 1.44269504f;
#pragma unroll
    for (int i = 0; i < 4; ++i) {
      int jt = jtg * 4 + i;
      float4 v = *(const float4*)&bias[((long)h * 256 + rt * 16 + l15) * 256 + jt * 16 + quad * 4];
      v.x *= L; v.y *= L; v.z *= L; v.w *= L;
      *(float4*)&biasT[(((long)hb * 16 + jt) * 64 + lane) * 4] = v;
    }
  }
}

// ---------- GEMM body: C = A(bf16 [M][512]) * Bt(bf16 [N][512])^T + bias ----------
// 128x128 tile, BK=64, 4 waves, 4x4 MFMA 16x16x32 tiles per wave.
// LDS chunk-major [c][row][32] with XOR swizzle (pos = g ^ ((row>>1)&3)).
// EPI=0: q/k cols -> natural [32768][1024] bf16; v cols -> v^T [(b*8+h)*64+d][8192] bf16.
// EPI=1: fp32 row-major [32768][512] output (d_out).

template <int EPI>
__device__ __forceinline__ void gemm_body(const u16* __restrict__ A, const u16* __restrict__ Bt,
                                          const float* __restrict__ bias,
                                          u16* __restrict__ oqk, u16* __restrict__ ovt,
                                          float* __restrict__ ofp,
                                          long arow0, long brow0) {
  constexpr int K = 512;
  __shared__ u16 Asm[8192];
  __shared__ u16 Bsm[8192];

  const int tid = threadIdx.x;
  const int wave = tid >> 6, lane = tid & 63;
  const int quad = lane >> 4, l15 = lane & 15;
  const int wm = wave >> 1, wn = wave & 1;
  const int gsw = quad ^ ((l15 >> 1) & 3);

  f32x4 acc[4][4] = {};

  for (int k0 = 0; k0 < K; k0 += 64) {
#pragma unroll
    for (int rd = 0; rd < 4; ++rd) {
      int flat = rd * 256 + tid;  // 16B-block index 0..1023
      int c = flat >> 9, row = (flat >> 2) & 127, gp = flat & 3;
      int g = gp ^ ((row >> 1) & 3);
      const long koff = k0 + c * 32 + g * 8;
      glds16(A + (arow0 + row) * K + koff, &Asm[(rd * 256 + wave * 64) * 8]);
      glds16(Bt + (brow0 + row) * K + koff, &Bsm[(rd * 256 + wave * 64) * 8]);
    }
    __syncthreads();
#pragma unroll
    for (int c = 0; c < 2; ++c) {
      bf16x8 af[4], bfr[4];
#pragma unroll
      for (int i = 0; i < 4; ++i)
        af[i] = *(const bf16x8*)&Asm[c * 4096 + (wm * 64 + i * 16 + l15) * 32 + gsw * 8];
#pragma unroll
      for (int j = 0; j < 4; ++j)
        bfr[j] = *(const bf16x8*)&Bsm[c * 4096 + (wn * 64 + j * 16 + l15) * 32 + gsw * 8];
#pragma unroll
      for (int i = 0; i < 4; ++i)
#pragma unroll
        for (int j = 0; j < 4; ++j)
          acc[i][j] = mfma16(af[i], bfr[j], acc[i][j]);
    }
    __syncthreads();
  }

  // epilogue: D-layout row = quad*4 + r, col = l15
#pragma unroll
  for (int j = 0; j < 4; ++j) {
    const int C = (int)brow0 + wn * 64 + j * 16 + l15;
    const float bc = bias[C];
#pragma unroll
    for (int i = 0; i < 4; ++i) {
      const long R0 = arow0 + wm * 64 + i * 16 + quad * 4;
      float v4[4];
#pragma unroll
      for (int r = 0; r < 4; ++r) v4[r] = acc[i][j][r] + bc;
      if constexpr (EPI == 0) {
        if (C < 1024) {  // q/k: natural rows (wave-uniform branch)
#pragma unroll
          for (int r = 0; r < 4; ++r) oqk[(R0 + r) * 1024 + C] = f2bf(v4[r]);
        } else {         // v: transposed, packed 8B along n
          const int hc = (C >> 6) & 7, dc = C & 63;
          const int b = (int)(R0 >> 13), n0 = (int)(R0 & 8191);
          uint2 w;
          w.x = pk2(v4[0], v4[1]);
          w.y = pk2(v4[2], v4[3]);
          *(uint2*)&ovt[((long)(b * 8 + hc) * 64 + dc) * 8192 + n0] = w;
        }
      } else {
#pragma unroll
        for (int r = 0; r < 4; ++r) ofp[(R0 + r) * 512 + C] = v4[r];
      }
    }
  }
}

// XCD-aware swizzle (heuristic, perf-only): xcd = bid % 8 owns a contiguous band of
// 32 M-tiles; N fastest within the band -> each A-tile lives in exactly one XCD L2,
// B stays resident.

__launch_bounds__(256)
__global__ void qkv_gemm_k(const u16* __restrict__ A, const u16* __restrict__ Bt,
                           const float* __restrict__ bias,
                           u16* __restrict__ oqk, u16* __restrict__ ovt) {
  int bid = blockIdx.x;               // 3072 = 8 xcd * 32 mt * 12 nt
  int xcd = bid & 7, i = bid >> 3;
  int nt = i % 12, mtl = i / 12;
  gemm_body<0>(A, Bt, bias, oqk, ovt, nullptr,
               (long)(xcd * 32 + mtl) * 128, (long)nt * 128);
}

__launch_bounds__(256)
__global__ void proj_gemm_k(const u16* __restrict__ A, const u16* __restrict__ Bt,
                            const float* __restrict__ bias, float* __restrict__ ofp) {
  int bid = blockIdx.x;               // 1024 = 8 xcd * 32 mt * 4 nt
  int xcd = bid & 7, i = bid >> 3;
  int nt = i & 3, mtl = i >> 2;
  gemm_body<1>(A, Bt, bias, nullptr, nullptr, ofp,
               (long)(xcd * 32 + mtl) * 128, (long)nt * 128);
}

// ---------- attention: one 512-thread block per (b,h,window) ----------
// S^T = K Q^T formulation, streaming no-max softmax (scores bounded ~|2|).
// XCD swizzle clusters the 8 heads of a window on one XCD (q/k rows share lines).
// q frags hoisted above the barrier to overlap staging.

__launch_bounds__(512, 4)
__global__ void attn_win(const u16* __restrict__ qk, const u16* __restrict__ vtb,
                         const float* __restrict__ biasT, u16* __restrict__ og) {
  __shared__ __align__(16) u16 kS[16384];    // [c][256 t][32], pos = g^((t>>1)&3)   32 KB
  __shared__ __align__(16) u16 vS[16384];    // [kk 8][64 d][32], pos = g^((d>>1)&3) 32 KB
  __shared__ __align__(16) u16 pS[8][1024];  // per-wave 2 slots x [16 q][32 t]      16 KB

  const int tid = threadIdx.x;
  const int wave = tid >> 6, lane = tid & 63;
  const int quad = lane >> 4, l15 = lane & 15;
  const int gsw = quad ^ ((l15 >> 1) & 3);

  // swizzle: 1024 = 8 xcd * 8 h * 16 wl ; window = xcd*16 + wl  (all 8 heads co-XCD)
  const int wi = blockIdx.x;
  const int xcd = wi & 7, hi = (wi >> 3) & 7, wl = wi >> 6;
  const int win = xcd * 16 + wl;             // [0,128)
  const int nwi = win & 31, bi = win >> 5;
  const long grow = (long)bi * 8192 + nwi * 256;
  const u16* qp = qk + grow * 1024 + hi * 64;
  const u16* kp = qp + 512;
  const u16* vp = vtb + (long)(bi * 8 + hi) * 64 * 8192 + nwi * 256;  // [d][256]

  // q B-frags for both sub-chunks, issued before the barrier (overlap staging)
  bf16x8 bq[2][2];
#pragma unroll
  for (int sc = 0; sc < 2; ++sc) {
    const int q0 = wave * 32 + sc * 16;
    bq[sc][0] = *(const bf16x8*)&qp[(long)(q0 + l15) * 1024 + quad * 8];
    bq[sc][1] = *(const bf16x8*)&qp[(long)(q0 + l15) * 1024 + 32 + quad * 8];
  }

  // stage k rows -> chunk-major swizzled LDS (512 threads: 4 iters)
#pragma unroll
  for (int it = 0; it < 4; ++it) {
    int flat = it * 512 + tid;
    int t = flat >> 3, dg = flat & 7;
    int c = dg >> 2, gp = (dg & 3) ^ ((t >> 1) & 3);
    int4 val = *(const int4*)&kp[(long)t * 1024 + dg * 8];
    *(int4*)&kS[c * 8192 + t * 32 + gp * 8] = val;
  }
  // stage v^T rows -> chunk-major swizzled LDS (coalesced 512B/d-row)
#pragma unroll
  for (int it = 0; it < 4; ++it) {
    int flat = it * 512 + tid;
    int d = flat >> 5, tg = flat & 31;
    int kk = tg >> 2, gp = (tg & 3) ^ ((d >> 1) & 3);
    int4 val = *(const int4*)&vp[(long)d * 8192 + tg * 8];
    *(int4*)&vS[kk * 2048 + d * 32 + gp * 8] = val;
  }
  __syncthreads();

  u16* Pw = pS[wave];
  const float cscale = 0.18033688f;  // 64^-0.5 * log2(e)

#pragma unroll
  for (int sc = 0; sc < 2; ++sc) {
    const int q0 = wave * 32 + sc * 16;
    const int rt = wave * 2 + sc;
    const float* bT = &biasT[(long)(hi * 16 + rt) * 16 * 64 * 4];

    f32x4 sum4 = {0.f, 0.f, 0.f, 0.f};
    f32x4 o[4] = {};

#pragma unroll
    for (int m = 0; m < 4; ++m) {
      // S-stream: 4 jt -> exp2 -> P slots (kk = m*2, m*2+1)
#pragma unroll
      for (int j2 = 0; j2 < 4; ++j2) {
        const int jt = m * 4 + j2;
        bf16x8 a0 = *(const bf16x8*)&kS[(jt * 16 + l15) * 32 + gsw * 8];
        bf16x8 a1 = *(const bf16x8*)&kS[8192 + (jt * 16 + l15) * 32 + gsw * 8];
        f32x4 z = {0.f, 0.f, 0.f, 0.f};
        z = mfma16(a0, bq[sc][0], z);
        z = mfma16(a1, bq[sc][1], z);
        f32x4 bb = *(const f32x4*)&bT[(long)jt * 256 + lane * 4];
        f32x4 p;
#pragma unroll
        for (int r = 0; r < 4; ++r) {
          p[r] = __builtin_exp2f(z[r] * cscale + bb[r]);
          sum4[r] += p[r];
        }
        const int gp = ((jt & 1) * 2 + (quad >> 1)) ^ ((l15 >> 1) & 3);
        const int slot = (jt >> 1) & 1;
        uint2 w;
        w.x = pk2(p[0], p[1]);
        w.y = pk2(p[2], p[3]);
        *(uint2*)&Pw[slot * 512 + l15 * 32 + gp * 8 + (quad & 1) * 4] = w;
      }
      // PV for the 2 completed chunks (same-wave DS in-order; no barrier)
#pragma unroll
      for (int kk2 = 0; kk2 < 2; ++kk2) {
        const int kk = m * 2 + kk2;
        bf16x8 bp = *(const bf16x8*)&Pw[kk2 * 512 + l15 * 32 + gsw * 8];
#pragma unroll
        for (int dt = 0; dt < 4; ++dt) {
          bf16x8 av = *(const bf16x8*)&vS[kk * 2048 + (dt * 16 + l15) * 32 + gsw * 8];
          o[dt] = mfma16(av, bp, o[dt]);  // O^T[d][q]
        }
      }
    }

    // rowsum -> inv (q = l15 lives in-lane; 2 cross-quad shuffles)
    float sum = (sum4[0] + sum4[1]) + (sum4[2] + sum4[3]);
    sum += __shfl_xor(sum, 16);
    sum += __shfl_xor(sum, 32);
    const float inv = 1.0f / sum;

    // store: lane holds 4 consecutive d per dt at row n = grow+q0+l15 -> 8B packs
    const long rowoff = (grow + q0 + l15) * 512 + hi * 64 + quad * 4;
#pragma unroll
    for (int dt = 0; dt < 4; ++dt) {
      uint2 w;
      w.x = pk2(o[dt][0] * inv, o[dt][1] * inv);
      w.y = pk2(o[dt][2] * inv, o[dt][3] * inv);
      *(uint2*)&og[rowoff + dt * 16] = w;
    }
  }
}

// ---------- launcher ----------

extern "C" void kernel_launch(void* const* d_in, const int* in_sizes, int n_in,
                              void* d_out, int out_size, void* d_ws, size_t ws_size,
                              hipStream_t stream) {
  const float* x     = (const float*)d_in[0];
  const float* Wqkv  = (const float*)d_in[1];
  const float* bqkv  = (const float*)d_in[2];
  const float* Wproj = (const float*)d_in[3];
  const float* bproj = (const float*)d_in[4];
  const float* abias = (const float*)d_in[5];
  float* out = (float*)d_out;

  // workspace layout (bytes):
  //   qk natural bf16 [32768][1024]: 67,108,864
  //   v^T bf16 [2048][8192]:         33,554,432   (ends 100,663,296)
  //   WqkvT bf16: 1,572,864 | WprojT bf16: 524,288 | biasT fp32: 2,097,152
  //   x_bf16 [32768][512] (aliased as attn_out after qkv GEMM): 33,554,432
  char* ws = (char*)d_ws;
  u16*   qkp    = (u16*)(ws);
  u16*   vtb    = (u16*)(ws + 67108864L);
  u16*   wqkvT  = (u16*)(ws + 100663296L);
  u16*   wprojT = (u16*)(ws + 102236160L);
  float* biasTp = (float*)(ws + 102760448L);
  u16*   xbf    = (u16*)(ws + 104857600L);
  u16*   attnout = xbf;  // safe: x_bf16 dead after qkv GEMM (stream-ordered)

  prep_k<<<9344, 256, 0, stream>>>(x, xbf, Wqkv, wqkvT, Wproj, wprojT, abias, biasTp);
  qkv_gemm_k<<<3072, 256, 0, stream>>>(xbf, wqkvT, bqkv, qkp, vtb);
  attn_win<<<1024, 512, 0, stream>>>(qkp, vtb, biasTp, attnout);
  proj_gemm_k<<<1024, 256, 0, stream>>>(attnout, wprojT, bproj, out);
}